// Round 1
// 234.126 us; speedup vs baseline: 1.0026x; 1.0026x over previous
//
#include <hip/hip_runtime.h>

#define BZ    167              // grid3d_index dims 0/1 (SIZE + 2*MARGIN)
#define BZ2   83               // BZ/2
#define NX    84               // BZ/2 + 1  (last axis)
#define NCELL (BZ * BZ * NX)   // 2,342,676 cells
#define NBX   51               // ceil(13041/256) blocks/batch (fallback tiers)
#define NBX2  102              // ceil(13041/128) blocks/batch (half-lane kernel)
#define NBQ   204              // ceil(13041/64)  blocks/batch (quarter-lane kernel)

// ---- bf16 helpers (round-to-nearest-even pack, free unpack) ----
static __device__ __forceinline__ unsigned f2bf(float f) {
    unsigned u = __float_as_uint(f);
    return (u + 0x7FFFu + ((u >> 16) & 1u)) >> 16;
}
static __device__ __forceinline__ float bf_lo(unsigned u) {
    return __uint_as_float(u << 16);
}
static __device__ __forceinline__ float bf_hi(unsigned u) {
    return __uint_as_float(u & 0xFFFF0000u);
}

// ---- fused pre-pass (quad tier): pack weights fp32->bf16 AND build
// gpair[cell] = (j(cell), bias(cell), j(cell+1), bias(cell+1)) — the two
// x-adjacent corner cells of every trilinear corner pair, 16B aligned so the
// main kernel fetches both corners' (j,bias) in ONE int4 gather ----
__global__ __launch_bounds__(256) void pack_all2(
    const float4* __restrict__ wsrc, uint2* __restrict__ wdst, int nw4, int nbw,
    const int* __restrict__ grid, const float* __restrict__ bias,
    int4* __restrict__ gpair, int ncell)
{
    if ((int)blockIdx.x < nbw) {
        const int i = blockIdx.x * 256 + threadIdx.x;
        if (i >= nw4) return;
        const float4 v = wsrc[i];
        wdst[i] = make_uint2(f2bf(v.x) | (f2bf(v.y) << 16),
                             f2bf(v.z) | (f2bf(v.w) << 16));
    } else {
        const int i = ((int)blockIdx.x - nbw) * 256 + threadIdx.x;
        if (i >= ncell) return;
        const int j0 = grid[i];
        const int j1 = (i + 1 < ncell) ? grid[i + 1] : -1;
        unsigned b0 = 0u, b1 = 0u;
        if (j0 >= 0)
            b0 = f2bf(bias[2 * j0]) | (f2bf(bias[2 * j0 + 1]) << 16);
        if (j1 >= 0)
            b1 = f2bf(bias[2 * j1]) | (f2bf(bias[2 * j1 + 1]) << 16);
        gpair[i] = make_int4(j0, (int)b0, j1, (int)b1);
    }
}

// ============== main kernel: quarter-lane (4 lanes per point) ================
// Lane quad bits: bit0 = input half h (dims 4h..4h+3), bit1 = corner dx.
// Per point: 4 gpair int4 gathers (quad-shared address, covers all 8 corner
// cells' (j,bias)) + 4 wpk uint4 gathers (each instruction covers a 64B
// x-adjacent record PAIR per point -> interior corners coalesce into one
// 128B line lookup). Line-lookups/point drop 16 -> ~9 vs svr_half.
__global__ __launch_bounds__(256, 4) void svr_quad(
    const float*    __restrict__ input,   // (B, 8)
    const unsigned* __restrict__ wpk,     // (W, 8) uints = 16 bf16
    const int4*     __restrict__ gpair,   // (NCELL): (j0, bias0, j1, bias1)
    const float*    __restrict__ rot,     // (B, 3, 3)
    const float*    __restrict__ coord,   // (P, 2)
    const int*      __restrict__ max_r,
    float*          __restrict__ out,     // (B, P, 2)
    int P)
{
    const int m    = blockIdx.x;
    const int xcd  = m & 7;                    // XCD-aware batch striping
    const int slot = m >> 3;
    const int b    = (slot / NBQ) * 8 + xcd;
    const int lane = threadIdx.x;
    const int q    = lane & 3;                 // quad lane
    const int h    = q & 1;                    // input half
    const int dxl  = q >> 1;                   // this lane's corner dx
    const int p    = (slot % NBQ) * 64 + (lane >> 2);
    if (p >= P) return;

    const float2 xy = *(const float2*)(coord + 2 * p);
    const float x = xy.x, y = xy.y;

    const int mr = min(max_r[0], (BZ - 6) / 2);
    const bool valid = (x * x + y * y) <= (float)(mr * mr);

    float2* o = (float2*)(out + ((size_t)b * P + p) * 2);
    if (!valid) {
        if (q == 0) *o = make_float2(0.f, 0.f);
        return;
    }

    const float* R = rot + b * 9;
    float cx = fmaf(R[1], y, R[0] * x);
    float cy = fmaf(R[4], y, R[3] * x);
    float cz = fmaf(R[7], y, R[6] * x);

    float sgn = 1.f;
    if (cx < 0.f) { cx = -cx; cy = -cy; cz = -cz; sgn = -1.f; }

    const float fx = floorf(cx), fy = floorf(cy), fz = floorf(cz);
    const float tx = cx - fx, ty = cy - fy, tz = cz - fz;
    const int ix = (int)fx;
    const int iy = (int)fy + BZ2;
    const int iz = (int)fz + BZ2;

    // ---- 4 quad-shared (j,bias)x2 gathers, all issued before any use ----
    int4 Gp[4];                 // i = dz*2 + dy
    #pragma unroll
    for (int i = 0; i < 4; ++i) {
        const int dy = i & 1, dz = i >> 1;
        Gp[i] = gpair[((iz + dz) * BZ + (iy + dy)) * NX + ix];
    }

    // this lane's half of input[b] (16B aligned)
    const float4 ih = *(const float4*)(input + b * 8 + h * 4);

    // per-lane corner weights: fixed dx factor x per-i (dy,dz) factor
    const float wxd = dxl ? tx : 1.f - tx;
    float wyz[4];
    wyz[0] = (1.f - ty) * (1.f - tz);
    wyz[1] = ty * (1.f - tz);
    wyz[2] = (1.f - ty) * tz;
    wyz[3] = ty * tz;

    int jj[4]; unsigned bbl[4]; float wcl[4];
    #pragma unroll
    for (int i = 0; i < 4; ++i) {
        const int j = dxl ? Gp[i].z : Gp[i].x;
        bbl[i] = (unsigned)(dxl ? Gp[i].w : Gp[i].y);
        wcl[i] = (j >= 0) ? wxd * wyz[i] : 0.f;
        jj[i]  = max(j, 0);
    }

    // ---- 4 record gathers: lane quad covers the 64B x-adjacent record pair;
    // with the 128-VGPR budget all 4 (+4 gpair) stay in flight ----
    uint4 U[4];
    #pragma unroll
    for (int i = 0; i < 4; ++i)
        U[i] = *(const uint4*)(wpk + (size_t)jj[i] * 8 + h * 4);

    float acc0 = 0.f, acc1 = 0.f;
    #pragma unroll
    for (int i = 0; i < 4; ++i) {
        const float w = wcl[i];
        const unsigned bb = bbl[i];
        // bias contributes once per corner: h==0 lane only
        float v0 = h ? 0.f : bf_lo(bb);
        float v1 = h ? 0.f : bf_hi(bb);
        v0 = fmaf(ih.x, bf_lo(U[i].x), v0); v1 = fmaf(ih.x, bf_hi(U[i].x), v1);
        v0 = fmaf(ih.y, bf_lo(U[i].y), v0); v1 = fmaf(ih.y, bf_hi(U[i].y), v1);
        v0 = fmaf(ih.z, bf_lo(U[i].z), v0); v1 = fmaf(ih.z, bf_hi(U[i].z), v1);
        v0 = fmaf(ih.w, bf_lo(U[i].w), v0); v1 = fmaf(ih.w, bf_hi(U[i].w), v1);
        acc0 = fmaf(w, v0, acc0);
        acc1 = fmaf(w, v1, acc1);
    }

    // combine input halves (xor 1) then dx halves (xor 2) within the quad
    acc0 += __shfl_xor(acc0, 1);
    acc1 += __shfl_xor(acc1, 1);
    acc0 += __shfl_xor(acc0, 2);
    acc1 += __shfl_xor(acc1, 2);

    if (q == 0) *o = make_float2(acc0, acc1 * sgn);
}

// ============ fallback tier 2: lane-paired half-record kernel ================
__global__ __launch_bounds__(256) void pack_all(
    const float4* __restrict__ wsrc, uint2* __restrict__ wdst, int nw4, int nbw,
    const int* __restrict__ grid, const float* __restrict__ bias,
    int2* __restrict__ garr, int ncell)
{
    if ((int)blockIdx.x < nbw) {
        const int i = blockIdx.x * 256 + threadIdx.x;
        if (i >= nw4) return;
        const float4 v = wsrc[i];
        wdst[i] = make_uint2(f2bf(v.x) | (f2bf(v.y) << 16),
                             f2bf(v.z) | (f2bf(v.w) << 16));
    } else {
        const int i = ((int)blockIdx.x - nbw) * 256 + threadIdx.x;
        if (i >= ncell) return;
        const int j = grid[i];
        unsigned bb = 0u;
        if (j >= 0)
            bb = f2bf(bias[2 * j]) | (f2bf(bias[2 * j + 1]) << 16);
        garr[i] = make_int2(j, (int)bb);
    }
}

__global__ __launch_bounds__(256, 4) void svr_half(
    const float*    __restrict__ input,   // (B, 8)
    const unsigned* __restrict__ wpk,     // (W, 8) uints = 16 bf16
    const int2*     __restrict__ garr,    // (NCELL): (j, bias bf16x2)
    const float*    __restrict__ rot,     // (B, 3, 3)
    const float*    __restrict__ coord,   // (P, 2)
    const int*      __restrict__ max_r,
    float*          __restrict__ out,     // (B, P, 2)
    int P)
{
    const int m    = blockIdx.x;
    const int xcd  = m & 7;
    const int slot = m >> 3;
    const int b    = (slot / NBX2) * 8 + xcd;
    const int lane = threadIdx.x;
    const int half = lane & 1;
    const int p    = (slot % NBX2) * 128 + (lane >> 1);
    if (p >= P) return;

    const float2 xy = *(const float2*)(coord + 2 * p);
    const float x = xy.x, y = xy.y;

    const int mr = min(max_r[0], (BZ - 6) / 2);
    const bool valid = (x * x + y * y) <= (float)(mr * mr);

    float* o = out + (((size_t)b * P + p) * 2 + half);
    if (!valid) {
        *o = 0.f;
        return;
    }

    const float* R = rot + b * 9;
    float cx = fmaf(R[1], y, R[0] * x);
    float cy = fmaf(R[4], y, R[3] * x);
    float cz = fmaf(R[7], y, R[6] * x);

    float sgn = 1.f;
    if (cx < 0.f) { cx = -cx; cy = -cy; cz = -cz; sgn = -1.f; }

    const float fx = floorf(cx), fy = floorf(cy), fz = floorf(cz);
    const float tx = cx - fx, ty = cy - fy, tz = cz - fz;
    const int ix = (int)fx;
    const int iy = (int)fy + BZ2;
    const int iz = (int)fz + BZ2;

    const float4 ih = *(const float4*)(input + b * 8 + half * 4);

    int2 G[8];
    #pragma unroll
    for (int dz = 0; dz < 2; ++dz) {
        #pragma unroll
        for (int dy = 0; dy < 2; ++dy) {
            const int base = ((iz + dz) * BZ + (iy + dy)) * NX + ix;
            const int c = dz * 4 + dy * 2;
            G[c + 0] = garr[base + 0];
            G[c + 1] = garr[base + 1];
        }
    }

    int   jj[8];
    float wc[8];
    {
        const float wx0 = 1.f - tx, wy0 = 1.f - ty, wz0 = 1.f - tz;
        #pragma unroll
        for (int c = 0; c < 8; ++c) {
            const int dx = c & 1, dy = (c >> 1) & 1, dz = c >> 2;
            const float w = (dx ? tx : wx0) * (dy ? ty : wy0) * (dz ? tz : wz0);
            const int j = G[c].x;
            wc[c] = (j >= 0) ? w : 0.f;
            jj[c] = max(j, 0);
        }
    }

    uint4 U[8];
    #pragma unroll
    for (int c = 0; c < 8; ++c)
        U[c] = *(const uint4*)(wpk + (size_t)jj[c] * 8 + half * 4);

    float acc0 = 0.f, acc1 = 0.f;
    #pragma unroll
    for (int c = 0; c < 8; ++c) {
        const float w = wc[c];
        const unsigned bb = (unsigned)G[c].y;
        float v0 = half ? 0.f : bf_lo(bb);
        float v1 = half ? 0.f : bf_hi(bb);
        v0 = fmaf(ih.x, bf_lo(U[c].x), v0); v1 = fmaf(ih.x, bf_hi(U[c].x), v1);
        v0 = fmaf(ih.y, bf_lo(U[c].y), v0); v1 = fmaf(ih.y, bf_hi(U[c].y), v1);
        v0 = fmaf(ih.z, bf_lo(U[c].z), v0); v1 = fmaf(ih.z, bf_hi(U[c].z), v1);
        v0 = fmaf(ih.w, bf_lo(U[c].w), v0); v1 = fmaf(ih.w, bf_hi(U[c].w), v1);
        acc0 = fmaf(w, v0, acc0);
        acc1 = fmaf(w, v1, acc1);
    }

    const float t0 = acc0 + __shfl_xor(acc0, 1);
    const float t1 = (acc1 + __shfl_xor(acc1, 1)) * sgn;
    *o = half ? t1 : t0;
}

// ============ fallback tier 3: bf16 weights + separate bias ==================
__global__ __launch_bounds__(256) void pack_w(
    const float4* __restrict__ src, uint2* __restrict__ dst, int n)
{
    const int i = blockIdx.x * 256 + threadIdx.x;
    if (i >= n) return;
    const float4 v = src[i];
    dst[i] = make_uint2(f2bf(v.x) | (f2bf(v.y) << 16),
                        f2bf(v.z) | (f2bf(v.w) << 16));
}
__global__ __launch_bounds__(256) void pack_b(
    const float* __restrict__ bias, unsigned* __restrict__ bpk, int W)
{
    const int j = blockIdx.x * 256 + threadIdx.x;
    if (j >= W) return;
    bpk[j] = f2bf(bias[2 * j]) | (f2bf(bias[2 * j + 1]) << 16);
}

__global__ __launch_bounds__(256) void svr_bf16(
    const float* __restrict__ input, const unsigned* __restrict__ wpk,
    const unsigned* __restrict__ bpk, const int* __restrict__ grid3d,
    const float* __restrict__ rot, const float* __restrict__ coord,
    const int* __restrict__ max_r, float* __restrict__ out, int P)
{
    const int m    = blockIdx.x;
    const int xcd  = m & 7;
    const int slot = m >> 3;
    const int b    = (slot / NBX) * 8 + xcd;
    const int p    = (slot % NBX) * 256 + threadIdx.x;
    if (p >= P) return;

    const float x = coord[2 * p + 0];
    const float y = coord[2 * p + 1];
    const int mr = min(max_r[0], (BZ - 6) / 2);
    const bool valid = (x * x + y * y) <= (float)(mr * mr);
    float2* o = (float2*)(out + ((size_t)b * P + p) * 2);
    if (!valid) { *o = make_float2(0.f, 0.f); return; }

    const float* R = rot + b * 9;
    float cx = fmaf(R[1], y, R[0] * x);
    float cy = fmaf(R[4], y, R[3] * x);
    float cz = fmaf(R[7], y, R[6] * x);
    float sgn = 1.f;
    if (cx < 0.f) { cx = -cx; cy = -cy; cz = -cz; sgn = -1.f; }
    const float fx = floorf(cx), fy = floorf(cy), fz = floorf(cz);
    const float tx = cx - fx, ty = cy - fy, tz = cz - fz;
    const int ix = (int)fx, iy = (int)fy + BZ2, iz = (int)fz + BZ2;

    const float* ib = input + b * 8;
    const float in0 = ib[0], in1 = ib[1], in2 = ib[2], in3 = ib[3];
    const float in4 = ib[4], in5 = ib[5], in6 = ib[6], in7 = ib[7];

    int jj[8]; float wc[8];
    const float wx0 = 1.f - tx, wy0 = 1.f - ty, wz0 = 1.f - tz;
    #pragma unroll
    for (int dz = 0; dz < 2; ++dz)
        #pragma unroll
        for (int dy = 0; dy < 2; ++dy) {
            const int base = ((iz + dz) * BZ + (iy + dy)) * NX + ix;
            #pragma unroll
            for (int dx = 0; dx < 2; ++dx) {
                const int c = dz * 4 + dy * 2 + dx;
                const int j = grid3d[base + dx];
                const float w = (dx ? tx : wx0) * (dy ? ty : wy0) * (dz ? tz : wz0);
                wc[c] = (j >= 0) ? w : 0.f;
                jj[c] = max(j, 0);
            }
        }

    uint4 U0[8], U1[8]; unsigned BB[8];
    #pragma unroll
    for (int c = 0; c < 8; ++c) {
        const uint4* wp = (const uint4*)(wpk + (size_t)jj[c] * 8);
        U0[c] = wp[0]; U1[c] = wp[1]; BB[c] = bpk[jj[c]];
    }

    float acc0 = 0.f, acc1 = 0.f;
    #pragma unroll
    for (int c = 0; c < 8; ++c) {
        const float w = wc[c];
        float v0 = bf_lo(BB[c]), v1 = bf_hi(BB[c]);
        v0 = fmaf(in0, bf_lo(U0[c].x), v0); v1 = fmaf(in0, bf_hi(U0[c].x), v1);
        v0 = fmaf(in1, bf_lo(U0[c].y), v0); v1 = fmaf(in1, bf_hi(U0[c].y), v1);
        v0 = fmaf(in2, bf_lo(U0[c].z), v0); v1 = fmaf(in2, bf_hi(U0[c].z), v1);
        v0 = fmaf(in3, bf_lo(U0[c].w), v0); v1 = fmaf(in3, bf_hi(U0[c].w), v1);
        v0 = fmaf(in4, bf_lo(U1[c].x), v0); v1 = fmaf(in4, bf_hi(U1[c].x), v1);
        v0 = fmaf(in5, bf_lo(U1[c].y), v0); v1 = fmaf(in5, bf_hi(U1[c].y), v1);
        v0 = fmaf(in6, bf_lo(U1[c].z), v0); v1 = fmaf(in6, bf_hi(U1[c].z), v1);
        v0 = fmaf(in7, bf_lo(U1[c].w), v0); v1 = fmaf(in7, bf_hi(U1[c].w), v1);
        acc0 = fmaf(w, v0, acc0);
        acc1 = fmaf(w, v1, acc1);
    }
    *o = make_float2(acc0, acc1 * sgn);
}

// ============ fallback tier 4: direct fp32 (no workspace needed) =============
__global__ __launch_bounds__(256) void svr_fp32(
    const float* __restrict__ input, const float* __restrict__ weight,
    const float* __restrict__ bias, const int* __restrict__ grid3d,
    const float* __restrict__ rot, const float* __restrict__ coord,
    const int* __restrict__ max_r, float* __restrict__ out, int P)
{
    const int m    = blockIdx.x;
    const int xcd  = m & 7;
    const int slot = m >> 3;
    const int b    = (slot / NBX) * 8 + xcd;
    const int p    = (slot % NBX) * 256 + threadIdx.x;
    if (p >= P) return;

    const float x = coord[2 * p + 0];
    const float y = coord[2 * p + 1];
    const int mr = min(max_r[0], (BZ - 6) / 2);
    const bool valid = (x * x + y * y) <= (float)(mr * mr);
    float2* o = (float2*)(out + ((size_t)b * P + p) * 2);
    if (!valid) { *o = make_float2(0.f, 0.f); return; }

    const float* R = rot + b * 9;
    float cx = fmaf(R[1], y, R[0] * x);
    float cy = fmaf(R[4], y, R[3] * x);
    float cz = fmaf(R[7], y, R[6] * x);
    float sgn = 1.f;
    if (cx < 0.f) { cx = -cx; cy = -cy; cz = -cz; sgn = -1.f; }
    const float fx = floorf(cx), fy = floorf(cy), fz = floorf(cz);
    const float tx = cx - fx, ty = cy - fy, tz = cz - fz;
    const int ix = (int)fx, iy = (int)fy + BZ2, iz = (int)fz + BZ2;

    const float* ib = input + b * 8;
    const float in0 = ib[0], in1 = ib[1], in2 = ib[2], in3 = ib[3];
    const float in4 = ib[4], in5 = ib[5], in6 = ib[6], in7 = ib[7];

    int jj[8]; float wc[8];
    const float wx0 = 1.f - tx, wy0 = 1.f - ty, wz0 = 1.f - tz;
    #pragma unroll
    for (int dz = 0; dz < 2; ++dz)
        #pragma unroll
        for (int dy = 0; dy < 2; ++dy) {
            const int base = ((iz + dz) * BZ + (iy + dy)) * NX + ix;
            #pragma unroll
            for (int dx = 0; dx < 2; ++dx) {
                const int c = dz * 4 + dy * 2 + dx;
                const int j = grid3d[base + dx];
                const float w = (dx ? tx : wx0) * (dy ? ty : wy0) * (dz ? tz : wz0);
                wc[c] = (j >= 0) ? w : 0.f;
                jj[c] = max(j, 0);
            }
        }

    float acc0 = 0.f, acc1 = 0.f;
    #pragma unroll
    for (int c = 0; c < 8; ++c) {
        const size_t j = (size_t)jj[c];
        const float4* wp = (const float4*)(weight + j * 16);
        const float4 W0 = wp[0], W1 = wp[1], W2 = wp[2], W3 = wp[3];
        const float2 bb = *(const float2*)(bias + j * 2);
        const float w = wc[c];
        float v0 = bb.x, v1 = bb.y;
        v0 = fmaf(in0, W0.x, v0); v1 = fmaf(in0, W0.y, v1);
        v0 = fmaf(in1, W0.z, v0); v1 = fmaf(in1, W0.w, v1);
        v0 = fmaf(in2, W1.x, v0); v1 = fmaf(in2, W1.y, v1);
        v0 = fmaf(in3, W1.z, v0); v1 = fmaf(in3, W1.w, v1);
        v0 = fmaf(in4, W2.x, v0); v1 = fmaf(in4, W2.y, v1);
        v0 = fmaf(in5, W2.z, v0); v1 = fmaf(in5, W2.w, v1);
        v0 = fmaf(in6, W3.x, v0); v1 = fmaf(in6, W3.y, v1);
        v0 = fmaf(in7, W3.z, v0); v1 = fmaf(in7, W3.w, v1);
        acc0 = fmaf(w, v0, acc0);
        acc1 = fmaf(w, v1, acc1);
    }
    *o = make_float2(acc0, acc1 * sgn);
}

extern "C" void kernel_launch(void* const* d_in, const int* in_sizes, int n_in,
                              void* d_out, int out_size, void* d_ws, size_t ws_size,
                              hipStream_t stream) {
    const float* input  = (const float*)d_in[0];
    const float* weight = (const float*)d_in[1];
    const float* bias   = (const float*)d_in[2];
    const int*   grid3d = (const int*)  d_in[3];
    const float* rot    = (const float*)d_in[4];
    const float* coord  = (const float*)d_in[5];
    const int*   max_r  = (const int*)  d_in[6];
    float* out = (float*)d_out;

    const int P = in_sizes[5] / 2;        // 13041
    const int B = in_sizes[4] / 9;        // 256
    const int W = in_sizes[1] / 16;       // weight_count

    const size_t wpk_bytes  = (size_t)W * 32;
    const size_t need_quad  = wpk_bytes + (size_t)NCELL * 16;  // ~72 MB
    const size_t need_full  = wpk_bytes + (size_t)NCELL * 8;   // ~53 MB
    const size_t need_bf    = (size_t)W * 36;                  // ~39 MB

    dim3 block(256, 1, 1);

    if (ws_size >= need_quad) {
        unsigned* wpk = (unsigned*)d_ws;
        int4* gpair = (int4*)((char*)d_ws + wpk_bytes);
        const int nw4 = W * 4;
        const int nbw = (nw4 + 255) / 256;
        const int nbg = (NCELL + 255) / 256;
        pack_all2<<<nbw + nbg, block, 0, stream>>>(
            (const float4*)weight, (uint2*)wpk, nw4, nbw,
            grid3d, bias, gpair, NCELL);
        dim3 grid(NBQ * B, 1, 1);
        svr_quad<<<grid, block, 0, stream>>>(input, wpk, gpair, rot, coord,
                                             max_r, out, P);
    } else if (ws_size >= need_full) {
        unsigned* wpk = (unsigned*)d_ws;
        int2* garr = (int2*)((char*)d_ws + wpk_bytes);
        const int nw4 = W * 4;
        const int nbw = (nw4 + 255) / 256;
        const int nbg = (NCELL + 255) / 256;
        pack_all<<<nbw + nbg, block, 0, stream>>>(
            (const float4*)weight, (uint2*)wpk, nw4, nbw,
            grid3d, bias, garr, NCELL);
        dim3 grid(NBX2 * B, 1, 1);
        svr_half<<<grid, block, 0, stream>>>(input, wpk, garr, rot, coord,
                                             max_r, out, P);
    } else if (ws_size >= need_bf) {
        unsigned* wpk = (unsigned*)d_ws;
        unsigned* bpk = wpk + (size_t)W * 8;
        const int nw = W * 4;
        pack_w<<<(nw + 255) / 256, block, 0, stream>>>(
            (const float4*)weight, (uint2*)wpk, nw);
        pack_b<<<(W + 255) / 256, block, 0, stream>>>(bias, bpk, W);
        dim3 grid(NBX * B, 1, 1);
        svr_bf16<<<grid, block, 0, stream>>>(input, wpk, bpk, grid3d, rot,
                                             coord, max_r, out, P);
    } else {
        dim3 grid(NBX * B, 1, 1);
        svr_fp32<<<grid, block, 0, stream>>>(input, weight, bias, grid3d, rot,
                                             coord, max_r, out, P);
    }
}

// Round 2
// 232.619 us; speedup vs baseline: 1.0091x; 1.0065x over previous
//
#include <hip/hip_runtime.h>

#define BZ    167              // grid3d_index dims 0/1 (SIZE + 2*MARGIN)
#define BZ2   83               // BZ/2
#define NX    84               // BZ/2 + 1  (last axis)
#define NCELL (BZ * BZ * NX)   // 2,342,676 cells
#define NBX   51               // ceil(13041/256) blocks/batch (fallback tiers)
#define NBQ   204              // ceil(13041/64)  blocks/batch (quarter-lane kernel)

// ---- bf16 helpers (round-to-nearest-even pack, free unpack) ----
static __device__ __forceinline__ unsigned f2bf(float f) {
    unsigned u = __float_as_uint(f);
    return (u + 0x7FFFu + ((u >> 16) & 1u)) >> 16;
}
static __device__ __forceinline__ float bf_lo(unsigned u) {
    return __uint_as_float(u << 16);
}
static __device__ __forceinline__ float bf_hi(unsigned u) {
    return __uint_as_float(u & 0xFFFF0000u);
}

// ---- fused pre-pass: pack weights fp32->bf16 (coalesced float4->uint2) AND
// build garr[cell] = (j, bias bf16x2) in one dispatch ----
__global__ __launch_bounds__(256) void pack_all(
    const float4* __restrict__ wsrc, uint2* __restrict__ wdst, int nw4, int nbw,
    const int* __restrict__ grid, const float* __restrict__ bias,
    int2* __restrict__ garr, int ncell)
{
    if ((int)blockIdx.x < nbw) {
        const int i = blockIdx.x * 256 + threadIdx.x;
        if (i >= nw4) return;
        const float4 v = wsrc[i];
        wdst[i] = make_uint2(f2bf(v.x) | (f2bf(v.y) << 16),
                             f2bf(v.z) | (f2bf(v.w) << 16));
    } else {
        const int i = ((int)blockIdx.x - nbw) * 256 + threadIdx.x;
        if (i >= ncell) return;
        const int j = grid[i];
        unsigned bb = 0u;
        if (j >= 0)
            bb = f2bf(bias[2 * j]) | (f2bf(bias[2 * j + 1]) << 16);
        garr[i] = make_int2(j, (int)bb);
    }
}

// ============== main kernel: quarter-lane (4 lanes per point) ================
// Lane quad bits: bit0 = input half h (dims 4h..4h+3), bit1 = corner dx.
// Per point: 4 garr int2 gathers — lane's dx is folded into the ADDRESS
// (base + dxl), so one instruction covers both x-adjacent corner cells with
// 8B/lane and NO metadata redundancy (gpair's 16B/cell format duplicated
// every entry; garr is 19 MB vs 37 MB -> halves the per-batch L2-miss
// footprint, which is the binding path at ~3 TB/s).  4 wpk uint4 gathers:
// each covers a 64B x-adjacent record pair per point (interior corners
// coalesce into one 128B line lookup).
__global__ __launch_bounds__(256, 4) void svr_quad(
    const float*    __restrict__ input,   // (B, 8)
    const unsigned* __restrict__ wpk,     // (W, 8) uints = 16 bf16
    const int2*     __restrict__ garr,    // (NCELL): (j, bias bf16x2)
    const float*    __restrict__ rot,     // (B, 3, 3)
    const float*    __restrict__ coord,   // (P, 2)
    const int*      __restrict__ max_r,
    float*          __restrict__ out,     // (B, P, 2)
    int P)
{
    const int m    = blockIdx.x;
    const int xcd  = m & 7;                    // XCD-aware batch striping
    const int slot = m >> 3;
    const int b    = (slot / NBQ) * 8 + xcd;
    const int lane = threadIdx.x;
    const int q    = lane & 3;                 // quad lane
    const int h    = q & 1;                    // input half
    const int dxl  = q >> 1;                   // this lane's corner dx
    const int p    = (slot % NBQ) * 64 + (lane >> 2);
    if (p >= P) return;

    const float2 xy = *(const float2*)(coord + 2 * p);
    const float x = xy.x, y = xy.y;

    const int mr = min(max_r[0], (BZ - 6) / 2);
    const bool valid = (x * x + y * y) <= (float)(mr * mr);

    float2* o = (float2*)(out + ((size_t)b * P + p) * 2);
    if (!valid) {
        if (q == 0) *o = make_float2(0.f, 0.f);
        return;
    }

    const float* R = rot + b * 9;
    float cx = fmaf(R[1], y, R[0] * x);
    float cy = fmaf(R[4], y, R[3] * x);
    float cz = fmaf(R[7], y, R[6] * x);

    float sgn = 1.f;
    if (cx < 0.f) { cx = -cx; cy = -cy; cz = -cz; sgn = -1.f; }

    const float fx = floorf(cx), fy = floorf(cy), fz = floorf(cz);
    const float tx = cx - fx, ty = cy - fy, tz = cz - fz;
    const int ix = (int)fx;
    const int iy = (int)fy + BZ2;
    const int iz = (int)fz + BZ2;

    // ---- 4 (j,bias) gathers: lane's dx folded into the address; i = dz*2+dy
    const int base0 = (iz * BZ + iy) * NX + ix + dxl;
    int2 Gl[4];
    Gl[0] = garr[base0];                 // (dy0, dz0)
    Gl[1] = garr[base0 + NX];            // (dy1, dz0)
    Gl[2] = garr[base0 + NX * BZ];       // (dy0, dz1)
    Gl[3] = garr[base0 + NX * BZ + NX];  // (dy1, dz1)

    // this lane's half of input[b] (16B aligned)
    const float4 ih = *(const float4*)(input + b * 8 + h * 4);

    // per-lane corner weights: fixed dx factor x per-i (dy,dz) factor
    const float wxd = dxl ? tx : 1.f - tx;
    float wyz[4];
    wyz[0] = (1.f - ty) * (1.f - tz);
    wyz[1] = ty * (1.f - tz);
    wyz[2] = (1.f - ty) * tz;
    wyz[3] = ty * tz;

    int jj[4]; float wcl[4];
    #pragma unroll
    for (int i = 0; i < 4; ++i) {
        const int j = Gl[i].x;
        wcl[i] = (j >= 0) ? wxd * wyz[i] : 0.f;
        jj[i]  = max(j, 0);
    }

    // ---- 4 record gathers: lane quad covers the 64B x-adjacent record pair;
    // with the 128-VGPR budget all 4 (+4 garr) stay in flight ----
    uint4 U[4];
    #pragma unroll
    for (int i = 0; i < 4; ++i)
        U[i] = *(const uint4*)(wpk + (size_t)jj[i] * 8 + h * 4);

    float acc0 = 0.f, acc1 = 0.f;
    #pragma unroll
    for (int i = 0; i < 4; ++i) {
        const float w = wcl[i];
        const unsigned bb = (unsigned)Gl[i].y;
        // bias contributes once per corner: h==0 lane only
        float v0 = h ? 0.f : bf_lo(bb);
        float v1 = h ? 0.f : bf_hi(bb);
        v0 = fmaf(ih.x, bf_lo(U[i].x), v0); v1 = fmaf(ih.x, bf_hi(U[i].x), v1);
        v0 = fmaf(ih.y, bf_lo(U[i].y), v0); v1 = fmaf(ih.y, bf_hi(U[i].y), v1);
        v0 = fmaf(ih.z, bf_lo(U[i].z), v0); v1 = fmaf(ih.z, bf_hi(U[i].z), v1);
        v0 = fmaf(ih.w, bf_lo(U[i].w), v0); v1 = fmaf(ih.w, bf_hi(U[i].w), v1);
        acc0 = fmaf(w, v0, acc0);
        acc1 = fmaf(w, v1, acc1);
    }

    // combine input halves (xor 1) then dx halves (xor 2) within the quad
    acc0 += __shfl_xor(acc0, 1);
    acc1 += __shfl_xor(acc1, 1);
    acc0 += __shfl_xor(acc0, 2);
    acc1 += __shfl_xor(acc1, 2);

    if (q == 0) *o = make_float2(acc0, acc1 * sgn);
}

// ============ fallback tier 2: bf16 weights + separate bias ==================
__global__ __launch_bounds__(256) void pack_w(
    const float4* __restrict__ src, uint2* __restrict__ dst, int n)
{
    const int i = blockIdx.x * 256 + threadIdx.x;
    if (i >= n) return;
    const float4 v = src[i];
    dst[i] = make_uint2(f2bf(v.x) | (f2bf(v.y) << 16),
                        f2bf(v.z) | (f2bf(v.w) << 16));
}
__global__ __launch_bounds__(256) void pack_b(
    const float* __restrict__ bias, unsigned* __restrict__ bpk, int W)
{
    const int j = blockIdx.x * 256 + threadIdx.x;
    if (j >= W) return;
    bpk[j] = f2bf(bias[2 * j]) | (f2bf(bias[2 * j + 1]) << 16);
}

__global__ __launch_bounds__(256) void svr_bf16(
    const float* __restrict__ input, const unsigned* __restrict__ wpk,
    const unsigned* __restrict__ bpk, const int* __restrict__ grid3d,
    const float* __restrict__ rot, const float* __restrict__ coord,
    const int* __restrict__ max_r, float* __restrict__ out, int P)
{
    const int m    = blockIdx.x;
    const int xcd  = m & 7;
    const int slot = m >> 3;
    const int b    = (slot / NBX) * 8 + xcd;
    const int p    = (slot % NBX) * 256 + threadIdx.x;
    if (p >= P) return;

    const float x = coord[2 * p + 0];
    const float y = coord[2 * p + 1];
    const int mr = min(max_r[0], (BZ - 6) / 2);
    const bool valid = (x * x + y * y) <= (float)(mr * mr);
    float2* o = (float2*)(out + ((size_t)b * P + p) * 2);
    if (!valid) { *o = make_float2(0.f, 0.f); return; }

    const float* R = rot + b * 9;
    float cx = fmaf(R[1], y, R[0] * x);
    float cy = fmaf(R[4], y, R[3] * x);
    float cz = fmaf(R[7], y, R[6] * x);
    float sgn = 1.f;
    if (cx < 0.f) { cx = -cx; cy = -cy; cz = -cz; sgn = -1.f; }
    const float fx = floorf(cx), fy = floorf(cy), fz = floorf(cz);
    const float tx = cx - fx, ty = cy - fy, tz = cz - fz;
    const int ix = (int)fx, iy = (int)fy + BZ2, iz = (int)fz + BZ2;

    const float* ib = input + b * 8;
    const float in0 = ib[0], in1 = ib[1], in2 = ib[2], in3 = ib[3];
    const float in4 = ib[4], in5 = ib[5], in6 = ib[6], in7 = ib[7];

    int jj[8]; float wc[8];
    const float wx0 = 1.f - tx, wy0 = 1.f - ty, wz0 = 1.f - tz;
    #pragma unroll
    for (int dz = 0; dz < 2; ++dz)
        #pragma unroll
        for (int dy = 0; dy < 2; ++dy) {
            const int base = ((iz + dz) * BZ + (iy + dy)) * NX + ix;
            #pragma unroll
            for (int dx = 0; dx < 2; ++dx) {
                const int c = dz * 4 + dy * 2 + dx;
                const int j = grid3d[base + dx];
                const float w = (dx ? tx : wx0) * (dy ? ty : wy0) * (dz ? tz : wz0);
                wc[c] = (j >= 0) ? w : 0.f;
                jj[c] = max(j, 0);
            }
        }

    uint4 U0[8], U1[8]; unsigned BB[8];
    #pragma unroll
    for (int c = 0; c < 8; ++c) {
        const uint4* wp = (const uint4*)(wpk + (size_t)jj[c] * 8);
        U0[c] = wp[0]; U1[c] = wp[1]; BB[c] = bpk[jj[c]];
    }

    float acc0 = 0.f, acc1 = 0.f;
    #pragma unroll
    for (int c = 0; c < 8; ++c) {
        const float w = wc[c];
        float v0 = bf_lo(BB[c]), v1 = bf_hi(BB[c]);
        v0 = fmaf(in0, bf_lo(U0[c].x), v0); v1 = fmaf(in0, bf_hi(U0[c].x), v1);
        v0 = fmaf(in1, bf_lo(U0[c].y), v0); v1 = fmaf(in1, bf_hi(U0[c].y), v1);
        v0 = fmaf(in2, bf_lo(U0[c].z), v0); v1 = fmaf(in2, bf_hi(U0[c].z), v1);
        v0 = fmaf(in3, bf_lo(U0[c].w), v0); v1 = fmaf(in3, bf_hi(U0[c].w), v1);
        v0 = fmaf(in4, bf_lo(U1[c].x), v0); v1 = fmaf(in4, bf_hi(U1[c].x), v1);
        v0 = fmaf(in5, bf_lo(U1[c].y), v0); v1 = fmaf(in5, bf_hi(U1[c].y), v1);
        v0 = fmaf(in6, bf_lo(U1[c].z), v0); v1 = fmaf(in6, bf_hi(U1[c].z), v1);
        v0 = fmaf(in7, bf_lo(U1[c].w), v0); v1 = fmaf(in7, bf_hi(U1[c].w), v1);
        acc0 = fmaf(w, v0, acc0);
        acc1 = fmaf(w, v1, acc1);
    }
    *o = make_float2(acc0, acc1 * sgn);
}

// ============ fallback tier 3: direct fp32 (no workspace needed) =============
__global__ __launch_bounds__(256) void svr_fp32(
    const float* __restrict__ input, const float* __restrict__ weight,
    const float* __restrict__ bias, const int* __restrict__ grid3d,
    const float* __restrict__ rot, const float* __restrict__ coord,
    const int* __restrict__ max_r, float* __restrict__ out, int P)
{
    const int m    = blockIdx.x;
    const int xcd  = m & 7;
    const int slot = m >> 3;
    const int b    = (slot / NBX) * 8 + xcd;
    const int p    = (slot % NBX) * 256 + threadIdx.x;
    if (p >= P) return;

    const float x = coord[2 * p + 0];
    const float y = coord[2 * p + 1];
    const int mr = min(max_r[0], (BZ - 6) / 2);
    const bool valid = (x * x + y * y) <= (float)(mr * mr);
    float2* o = (float2*)(out + ((size_t)b * P + p) * 2);
    if (!valid) { *o = make_float2(0.f, 0.f); return; }

    const float* R = rot + b * 9;
    float cx = fmaf(R[1], y, R[0] * x);
    float cy = fmaf(R[4], y, R[3] * x);
    float cz = fmaf(R[7], y, R[6] * x);
    float sgn = 1.f;
    if (cx < 0.f) { cx = -cx; cy = -cy; cz = -cz; sgn = -1.f; }
    const float fx = floorf(cx), fy = floorf(cy), fz = floorf(cz);
    const float tx = cx - fx, ty = cy - fy, tz = cz - fz;
    const int ix = (int)fx, iy = (int)fy + BZ2, iz = (int)fz + BZ2;

    const float* ib = input + b * 8;
    const float in0 = ib[0], in1 = ib[1], in2 = ib[2], in3 = ib[3];
    const float in4 = ib[4], in5 = ib[5], in6 = ib[6], in7 = ib[7];

    int jj[8]; float wc[8];
    const float wx0 = 1.f - tx, wy0 = 1.f - ty, wz0 = 1.f - tz;
    #pragma unroll
    for (int dz = 0; dz < 2; ++dz)
        #pragma unroll
        for (int dy = 0; dy < 2; ++dy) {
            const int base = ((iz + dz) * BZ + (iy + dy)) * NX + ix;
            #pragma unroll
            for (int dx = 0; dx < 2; ++dx) {
                const int c = dz * 4 + dy * 2 + dx;
                const int j = grid3d[base + dx];
                const float w = (dx ? tx : wx0) * (dy ? ty : wy0) * (dz ? tz : wz0);
                wc[c] = (j >= 0) ? w : 0.f;
                jj[c] = max(j, 0);
            }
        }

    float acc0 = 0.f, acc1 = 0.f;
    #pragma unroll
    for (int c = 0; c < 8; ++c) {
        const size_t j = (size_t)jj[c];
        const float4* wp = (const float4*)(weight + j * 16);
        const float4 W0 = wp[0], W1 = wp[1], W2 = wp[2], W3 = wp[3];
        const float2 bb = *(const float2*)(bias + j * 2);
        const float w = wc[c];
        float v0 = bb.x, v1 = bb.y;
        v0 = fmaf(in0, W0.x, v0); v1 = fmaf(in0, W0.y, v1);
        v0 = fmaf(in1, W0.z, v0); v1 = fmaf(in1, W0.w, v1);
        v0 = fmaf(in2, W1.x, v0); v1 = fmaf(in2, W1.y, v1);
        v0 = fmaf(in3, W1.z, v0); v1 = fmaf(in3, W1.w, v1);
        v0 = fmaf(in4, W2.x, v0); v1 = fmaf(in4, W2.y, v1);
        v0 = fmaf(in5, W2.z, v0); v1 = fmaf(in5, W2.w, v1);
        v0 = fmaf(in6, W3.x, v0); v1 = fmaf(in6, W3.y, v1);
        v0 = fmaf(in7, W3.z, v0); v1 = fmaf(in7, W3.w, v1);
        acc0 = fmaf(w, v0, acc0);
        acc1 = fmaf(w, v1, acc1);
    }
    *o = make_float2(acc0, acc1 * sgn);
}

extern "C" void kernel_launch(void* const* d_in, const int* in_sizes, int n_in,
                              void* d_out, int out_size, void* d_ws, size_t ws_size,
                              hipStream_t stream) {
    const float* input  = (const float*)d_in[0];
    const float* weight = (const float*)d_in[1];
    const float* bias   = (const float*)d_in[2];
    const int*   grid3d = (const int*)  d_in[3];
    const float* rot    = (const float*)d_in[4];
    const float* coord  = (const float*)d_in[5];
    const int*   max_r  = (const int*)  d_in[6];
    float* out = (float*)d_out;

    const int P = in_sizes[5] / 2;        // 13041
    const int B = in_sizes[4] / 9;        // 256
    const int W = in_sizes[1] / 16;       // weight_count

    const size_t wpk_bytes  = (size_t)W * 32;
    const size_t garr_bytes = (size_t)NCELL * 8;
    const size_t need_full  = wpk_bytes + garr_bytes;   // ~53 MB
    const size_t need_bf    = (size_t)W * 36;           // ~39 MB

    dim3 block(256, 1, 1);

    if (ws_size >= need_full) {
        unsigned* wpk = (unsigned*)d_ws;
        int2* garr = (int2*)((char*)d_ws + wpk_bytes);
        const int nw4 = W * 4;
        const int nbw = (nw4 + 255) / 256;
        const int nbg = (NCELL + 255) / 256;
        pack_all<<<nbw + nbg, block, 0, stream>>>(
            (const float4*)weight, (uint2*)wpk, nw4, nbw,
            grid3d, bias, garr, NCELL);
        dim3 grid(NBQ * B, 1, 1);
        svr_quad<<<grid, block, 0, stream>>>(input, wpk, garr, rot, coord,
                                             max_r, out, P);
    } else if (ws_size >= need_bf) {
        unsigned* wpk = (unsigned*)d_ws;
        unsigned* bpk = wpk + (size_t)W * 8;
        const int nw = W * 4;
        pack_w<<<(nw + 255) / 256, block, 0, stream>>>(
            (const float4*)weight, (uint2*)wpk, nw);
        pack_b<<<(W + 255) / 256, block, 0, stream>>>(bias, bpk, W);
        dim3 grid(NBX * B, 1, 1);
        svr_bf16<<<grid, block, 0, stream>>>(input, wpk, bpk, grid3d, rot,
                                             coord, max_r, out, P);
    } else {
        dim3 grid(NBX * B, 1, 1);
        svr_fp32<<<grid, block, 0, stream>>>(input, weight, bias, grid3d, rot,
                                             coord, max_r, out, P);
    }
}